// Round 1
// baseline (99.686 us; speedup 1.0000x reference)
//
#include <hip/hip_runtime.h>
#include <math.h>

// GHM-BCE: out = mean(beta * bce), beta_i = N / (count_i/0.1 + 1e-12),
// count_i = #{ j : |g_j - g_i| <= 0.1 }, g = |sigmoid(logits) - targets|.

#define N        16384
#define BLOCK    256
#define JSPLIT   16
#define JCHUNK   (N / JSPLIT)        // 1024
#define DELTA_F  0.1f
#define EPS_F    1e-12f

// ---------------- Kernel A: per-element prep + zero counts ----------------
__global__ void __launch_bounds__(BLOCK)
ghm_prep(const float* __restrict__ logits,
         const float* __restrict__ targets,
         float* __restrict__ g,
         float* __restrict__ loss,
         int*   __restrict__ cnt) {
    int i = blockIdx.x * BLOCK + threadIdx.x;
    if (i < N) {
        float x = logits[i];
        float t = targets[i];
        float pred = 1.0f / (1.0f + expf(-x));
        g[i] = fabsf(pred - t);
        // stable BCE-with-logits: max(x,0) - x*t + log1p(exp(-|x|))
        float l = fmaxf(x, 0.0f) - x * t + log1pf(expf(-fabsf(x)));
        loss[i] = l;
        cnt[i] = 0;   // ws is poisoned to 0xAA each call — zero here
    }
}

// ---------------- Kernel B: N^2 pairwise window count ----------------
// grid = (N/BLOCK, JSPLIT). blockIdx.x picks the i-tile (one i per thread),
// blockIdx.y picks a 1024-wide j-chunk staged into LDS.
__global__ void __launch_bounds__(BLOCK)
ghm_pair(const float* __restrict__ g,
         int* __restrict__ cnt) {
    __shared__ float gj[JCHUNK];
    const int jbase = blockIdx.y * JCHUNK;
    // cooperative stage: 256 threads x 4 elems, coalesced
    #pragma unroll
    for (int k = threadIdx.x; k < JCHUNK; k += BLOCK) {
        gj[k] = g[jbase + k];
    }
    __syncthreads();

    const int i = blockIdx.x * BLOCK + threadIdx.x;
    const float gi = g[i];
    int c = 0;
    #pragma unroll 8
    for (int k = 0; k < JCHUNK; ++k) {
        // all 64 lanes read the same LDS address -> broadcast, no conflict
        c += (fabsf(gj[k] - gi) <= DELTA_F) ? 1 : 0;
    }
    atomicAdd(&cnt[i], c);
}

// ---------------- Kernel C: beta*loss weighted mean ----------------
__global__ void __launch_bounds__(BLOCK)
ghm_final(const float* __restrict__ loss,
          const int*   __restrict__ cnt,
          float* __restrict__ out) {
    float s = 0.0f;
    for (int i = threadIdx.x; i < N; i += BLOCK) {
        float GD   = (float)cnt[i] / DELTA_F;          // count / 0.1
        float beta = (float)N / (GD + EPS_F);
        s += beta * loss[i];
    }
    // wave64 shuffle reduction
    #pragma unroll
    for (int off = 32; off > 0; off >>= 1) {
        s += __shfl_down(s, off, 64);
    }
    __shared__ float smem[BLOCK / 64];
    const int lane = threadIdx.x & 63;
    const int wid  = threadIdx.x >> 6;
    if (lane == 0) smem[wid] = s;
    __syncthreads();
    if (threadIdx.x == 0) {
        float tot = 0.0f;
        #pragma unroll
        for (int w = 0; w < BLOCK / 64; ++w) tot += smem[w];
        out[0] = tot / (float)N;
    }
}

extern "C" void kernel_launch(void* const* d_in, const int* in_sizes, int n_in,
                              void* d_out, int out_size, void* d_ws, size_t ws_size,
                              hipStream_t stream) {
    const float* logits  = (const float*)d_in[0];
    const float* targets = (const float*)d_in[1];
    float* out = (float*)d_out;

    // workspace layout: g[N] f32 | loss[N] f32 | cnt[N] i32
    float* g    = (float*)d_ws;
    float* loss = g + N;
    int*   cnt  = (int*)(loss + N);

    ghm_prep<<<dim3(N / BLOCK), dim3(BLOCK), 0, stream>>>(logits, targets, g, loss, cnt);
    ghm_pair<<<dim3(N / BLOCK, JSPLIT), dim3(BLOCK), 0, stream>>>(g, cnt);
    ghm_final<<<dim3(1), dim3(BLOCK), 0, stream>>>(loss, cnt, out);
}

// Round 2
// 71.729 us; speedup vs baseline: 1.3898x; 1.3898x over previous
//
#include <hip/hip_runtime.h>
#include <math.h>

// GHM-BCE via counting sort + CDF order statistics (O(N) instead of O(N^2)).
// count_i = #{j: g_j <= g_i+0.1} - #{j: g_j < g_i-0.1}
// Full buckets below the boundary bucket come from the inclusive CDF;
// the boundary bucket itself is scanned exactly against the threshold.

#define N       16384
#define K       4096          // histogram bins over [0,1)
#define BLOCK   256
#define GRID    (N / BLOCK)   // 64
#define DELTA_F 0.1f
#define EPS_F   1e-12f

__device__ __forceinline__ int bucket_of(float v) {
    int b = (int)(v * (float)K);      // monotone in v; same fn for build & query
    b = b < 0 ? 0 : b;
    b = b > (K - 1) ? (K - 1) : b;
    return b;
}

// ---- K1: per-element g/loss + zero hist/wsum/ticket (ws is 0xAA-poisoned) ----
__global__ void __launch_bounds__(BLOCK)
k_prep(const float* __restrict__ logits, const float* __restrict__ targets,
       float* __restrict__ g, float* __restrict__ loss,
       int* __restrict__ hist, float* __restrict__ wsum, int* __restrict__ ticket) {
    int i = blockIdx.x * BLOCK + threadIdx.x;
    float x = logits[i];
    float t = targets[i];
    float pred = 1.0f / (1.0f + expf(-x));
    g[i] = fabsf(pred - t);
    loss[i] = fmaxf(x, 0.0f) - x * t + log1pf(expf(-fabsf(x)));
    if (i < K) hist[i] = 0;
    if (i == 0) { *wsum = 0.0f; *ticket = 0; }
}

// ---- K2: histogram ----
__global__ void __launch_bounds__(BLOCK)
k_hist(const float* __restrict__ g, int* __restrict__ hist) {
    int i = blockIdx.x * BLOCK + threadIdx.x;
    atomicAdd(&hist[bucket_of(g[i])], 1);
}

// ---- K3: single-block scan of 4096 bins -> inclusive cdf, bucket start, cursor ----
__global__ void __launch_bounds__(1024)
k_scan(const int* __restrict__ hist, int* __restrict__ cdf,
       int* __restrict__ start, int* __restrict__ cursor) {
    __shared__ int wsums[16];
    int t = threadIdx.x;                 // 1024 threads x 4 bins
    int h0 = hist[4 * t + 0], h1 = hist[4 * t + 1];
    int h2 = hist[4 * t + 2], h3 = hist[4 * t + 3];
    int s0 = h0, s1 = s0 + h1, s2 = s1 + h2, s3 = s2 + h3;
    int lane = t & 63, wid = t >> 6;
    // wave64 inclusive scan of per-thread sums
    int scan = s3;
    #pragma unroll
    for (int off = 1; off < 64; off <<= 1) {
        int v = __shfl_up(scan, off, 64);
        if (lane >= off) scan += v;
    }
    if (lane == 63) wsums[wid] = scan;
    __syncthreads();
    if (t == 0) {
        int acc = 0;
        #pragma unroll
        for (int w = 0; w < 16; ++w) { int v = wsums[w]; wsums[w] = acc; acc += v; }
    }
    __syncthreads();
    int excl = wsums[wid] + (scan - s3);   // exclusive prefix of this thread's bins
    cdf[4 * t + 0] = excl + s0;
    cdf[4 * t + 1] = excl + s1;
    cdf[4 * t + 2] = excl + s2;
    cdf[4 * t + 3] = excl + s3;
    int b0 = excl, b1 = excl + s0, b2 = excl + s1, b3 = excl + s2;
    start[4 * t + 0] = b0;  cursor[4 * t + 0] = b0;
    start[4 * t + 1] = b1;  cursor[4 * t + 1] = b1;
    start[4 * t + 2] = b2;  cursor[4 * t + 2] = b2;
    start[4 * t + 3] = b3;  cursor[4 * t + 3] = b3;
}

// ---- K4: counting-sort scatter ----
__global__ void __launch_bounds__(BLOCK)
k_scatter(const float* __restrict__ g, int* __restrict__ cursor,
          float* __restrict__ gs) {
    int i = blockIdx.x * BLOCK + threadIdx.x;
    float v = g[i];
    int pos = atomicAdd(&cursor[bucket_of(v)], 1);
    gs[pos] = v;
}

// ---- K5: per-i window count via CDF + boundary-bucket scan, then weighted mean ----
__global__ void __launch_bounds__(BLOCK)
k_count(const float* __restrict__ g, const float* __restrict__ loss,
        const float* __restrict__ gs, const int* __restrict__ cdf,
        const int* __restrict__ start, float* __restrict__ wsum,
        int* __restrict__ ticket, float* __restrict__ out) {
    int i = blockIdx.x * BLOCK + threadIdx.x;
    float gi = g[i];
    float hi = gi + DELTA_F;
    float lo = gi - DELTA_F;
    int bh = bucket_of(hi);
    int bl = bucket_of(lo);

    int cnt = (bh > 0) ? cdf[bh - 1] : 0;            // full buckets < bh
    int eh = cdf[bh];
    for (int p = start[bh]; p < eh; ++p) cnt += (gs[p] <= hi) ? 1 : 0;

    int below = (bl > 0) ? cdf[bl - 1] : 0;          // full buckets < bl
    int el = cdf[bl];
    for (int p = start[bl]; p < el; ++p) below += (gs[p] < lo) ? 1 : 0;

    cnt -= below;

    float GD   = (float)cnt / DELTA_F;
    float beta = (float)N / (GD + EPS_F);
    float val  = beta * loss[i];

    // block reduction: wave64 shuffle + LDS
    #pragma unroll
    for (int off = 32; off > 0; off >>= 1) val += __shfl_down(val, off, 64);
    __shared__ float sm[BLOCK / 64];
    int lane = threadIdx.x & 63, wid = threadIdx.x >> 6;
    if (lane == 0) sm[wid] = val;
    __syncthreads();
    if (threadIdx.x == 0) {
        float bs = 0.0f;
        #pragma unroll
        for (int w = 0; w < BLOCK / 64; ++w) bs += sm[w];
        atomicAdd(wsum, bs);
        __threadfence();
        int done = atomicAdd(ticket, 1);
        if (done == (int)gridDim.x - 1) {           // last block finalizes
            float total = atomicAdd(wsum, 0.0f);    // device-scope read
            out[0] = total / (float)N;
        }
    }
}

extern "C" void kernel_launch(void* const* d_in, const int* in_sizes, int n_in,
                              void* d_out, int out_size, void* d_ws, size_t ws_size,
                              hipStream_t stream) {
    const float* logits  = (const float*)d_in[0];
    const float* targets = (const float*)d_in[1];
    float* out = (float*)d_out;

    // ws layout (all 16B-aligned): g[N] | loss[N] | gs[N] | hist[K] | cdf[K]
    //                              | start[K] | cursor[K] | wsum | ticket
    float* g      = (float*)d_ws;
    float* loss   = g + N;
    float* gs     = loss + N;
    int*   hist   = (int*)(gs + N);
    int*   cdf    = hist + K;
    int*   start  = cdf + K;
    int*   cursor = start + K;
    float* wsum   = (float*)(cursor + K);
    int*   ticket = (int*)(wsum + 1);

    k_prep   <<<dim3(GRID), dim3(BLOCK), 0, stream>>>(logits, targets, g, loss, hist, wsum, ticket);
    k_hist   <<<dim3(GRID), dim3(BLOCK), 0, stream>>>(g, hist);
    k_scan   <<<dim3(1),    dim3(1024),  0, stream>>>(hist, cdf, start, cursor);
    k_scatter<<<dim3(GRID), dim3(BLOCK), 0, stream>>>(g, cursor, gs);
    k_count  <<<dim3(GRID), dim3(BLOCK), 0, stream>>>(g, loss, gs, cdf, start, wsum, ticket, out);
}